// Round 11
// baseline (297.170 us; speedup 1.0000x reference)
//
#include <hip/hip_runtime.h>
#include <hip/hip_bf16.h>

// B=4, N=2048, C=768, H=16, D=48. FP32 in/out.
// Pipeline: cvt(x,W->bf16) -> gemm_qkv (fused, writes MFMA-fragment layout
// directly) -> attn (pipelined P double-buffer) -> gemm_out.
#define B_ 4
#define N_ 2048
#define C_ 768
#define H_ 16
#define D_ 48
#define SCALE_ 0.14433756729740643f
#define LOG2E_ 1.44269504088896f

using bf16 = __hip_bfloat16;
using bf16x8 = __attribute__((ext_vector_type(8))) short;
using f32x4  = __attribute__((ext_vector_type(4))) float;
using f32x16 = __attribute__((ext_vector_type(16))) float;

#if defined(__has_builtin)
#if __has_builtin(__builtin_amdgcn_cvt_pk_bf16_f32)
#define HAS_PK_BF16 1
#endif
#endif

__device__ __forceinline__ unsigned short f2b(float f) {
  bf16 h = __float2bfloat16(f);
  return *reinterpret_cast<unsigned short*>(&h);
}
__device__ __forceinline__ unsigned int pack2(float lo, float hi) {
#ifdef HAS_PK_BF16
  typedef __bf16 bf16x2v __attribute__((ext_vector_type(2)));
  bf16x2v r = __builtin_amdgcn_cvt_pk_bf16_f32(lo, hi);
  union { bf16x2v v; unsigned int u; } cv; cv.v = r; return cv.u;
#else
  return (unsigned int)f2b(lo) | ((unsigned int)f2b(hi) << 16);
#endif
}
__device__ __forceinline__ uint4 ld8f_cvt(const float* p) {
  float4 a = *reinterpret_cast<const float4*>(p);
  float4 b = *reinterpret_cast<const float4*>(p + 4);
  uint4 u;
  u.x = pack2(a.x, a.y); u.y = pack2(a.z, a.w);
  u.z = pack2(b.x, b.y); u.w = pack2(b.z, b.w);
  return u;
}
__device__ __forceinline__ void gload_lds16(const bf16* g, bf16* l) {
  __builtin_amdgcn_global_load_lds(
      (const __attribute__((address_space(1))) unsigned int*)g,
      (__attribute__((address_space(3))) unsigned int*)l, 16, 0, 0);
}

// ---- Kernel 0: fp32 -> bf16 conversions (x, Wq|Wk|Wv stacked, Wo).
__global__ __launch_bounds__(256) void cvt_bf16(
    const float* __restrict__ x,  const float* __restrict__ wq,
    const float* __restrict__ wk, const float* __restrict__ wv,
    const float* __restrict__ wo,
    bf16* __restrict__ xb, bf16* __restrict__ wqkvb, bf16* __restrict__ wob)
{
  const int job = blockIdx.y;
  const float* src; bf16* dst; int n;
  if (job == 0)      { src = x;  dst = xb;              n = B_ * N_ * C_; }
  else if (job == 1) { src = wq; dst = wqkvb;           n = C_ * C_; }
  else if (job == 2) { src = wk; dst = wqkvb + C_ * C_; n = C_ * C_; }
  else if (job == 3) { src = wv; dst = wqkvb + 2 * C_ * C_; n = C_ * C_; }
  else               { src = wo; dst = wob;             n = C_ * C_; }
  const int stride = gridDim.x * 256 * 8;
  for (int i = (blockIdx.x * 256 + threadIdx.x) * 8; i < n; i += stride)
    *(uint4*)(dst + i) = ld8f_cvt(src + i);
}

// ---- Kernel 1: fused QKV GEMM. A=xb[8192x768], B=Wqkv[2304x768].
// Epilogue stages the C-tile in LDS and writes Q/K/V directly in the
// MFMA-fragment layouts attn reads (16B coalesced chunks). Q pre-scaled.
// Fragment layouts (per bh-slab of N*48 bf16, chunk = 8 elems = 16B):
//  Q,K: chunk idx = (kg*3+kc)*64 + g2*32 + m5 ; elem (n=kg*32+m5, d=kc*16+g2*8+j)
//  V:   chunk idx = ((kt*3+df)*2+hf)*64 + g4*16 + c ; elem (n=kt*64+hf*32+g4*8+j, d=df*16+c)
__global__ __launch_bounds__(256) void gemm_qkv(
    const bf16* __restrict__ A, const bf16* __restrict__ Bw,
    const float* __restrict__ bq, const float* __restrict__ bk,
    const float* __restrict__ bv,
    bf16* __restrict__ Q, bf16* __restrict__ K, bf16* __restrict__ V)
{
  __shared__ __align__(16) bf16 SH[2 * 128 * 64];   // As|Bs, reused as Cs
  bf16* As = SH;
  bf16* Bs = SH + 128 * 64;

  const int tid  = threadIdx.x;
  const int lane = tid & 63, wid = tid >> 6;
  const int wm = (wid >> 1) * 64, wn = (wid & 1) * 64;
  const int row0 = blockIdx.y * 128, col0 = blockIdx.x * 128;
  const int mb = lane & 15, g4 = lane >> 4;
  const int srow = lane >> 3;
  const int schunk = (lane & 7) ^ (srow & 7);

  f32x4 acc[4][4];
#pragma unroll
  for (int i = 0; i < 4; ++i)
#pragma unroll
    for (int j = 0; j < 4; ++j) acc[i][j] = (f32x4){0.f, 0.f, 0.f, 0.f};

  for (int k0 = 0; k0 < C_; k0 += 64) {
#pragma unroll
    for (int t = 0; t < 4; ++t) {
      const int rt = wid * 32 + t * 8;
      gload_lds16(A  + (size_t)(row0 + rt + srow) * C_ + k0 + schunk * 8,
                  As + rt * 64);
      gload_lds16(Bw + (size_t)(col0 + rt + srow) * C_ + k0 + schunk * 8,
                  Bs + rt * 64);
    }
    __syncthreads();
#pragma unroll
    for (int ks = 0; ks < 2; ++ks) {
      const int kchunk = ks * 4 + g4;
      bf16x8 af[4], bfr[4];
#pragma unroll
      for (int i = 0; i < 4; ++i) {
        const int row = wm + i * 16 + mb;
        af[i] = *(const bf16x8*)(As + row * 64 + (kchunk ^ (row & 7)) * 8);
      }
#pragma unroll
      for (int j = 0; j < 4; ++j) {
        const int col = wn + j * 16 + mb;
        bfr[j] = *(const bf16x8*)(Bs + col * 64 + (kchunk ^ (col & 7)) * 8);
      }
#pragma unroll
      for (int i = 0; i < 4; ++i)
#pragma unroll
        for (int j = 0; j < 4; ++j)
          acc[i][j] = __builtin_amdgcn_mfma_f32_16x16x32_bf16(af[i], bfr[j], acc[i][j], 0, 0, 0);
    }
    __syncthreads();
  }

  const int z = blockIdx.x / 6;
  const float* bias = (z == 0) ? bq : (z == 1) ? bk : bv;
  bf16* dst = (z == 0) ? Q : (z == 1) ? K : V;
  const float sc = (z == 0) ? (SCALE_ * LOG2E_) : 1.0f;
  const int obase = (blockIdx.x % 6) * 128;
  bf16* Cs = SH;

#pragma unroll 1
  for (int h2 = 0; h2 < 2; ++h2) {
    __syncthreads();
    if ((wid >> 1) == h2) {          // the 2 waves owning these 64 rows stage
      if (z < 2) {
        // row-major [rowL][136] (272B row stride: 16B-aligned b128 reads)
#pragma unroll
        for (int j = 0; j < 4; ++j) {
          const int col = wn + j * 16 + mb;
          const float bb = bias[obase + col];
#pragma unroll
          for (int i = 0; i < 4; ++i)
#pragma unroll
            for (int reg = 0; reg < 4; ++reg) {
              const int rowL = i * 16 + 4 * g4 + reg;
              Cs[rowL * 136 + col] =
                  __float2bfloat16((acc[i][j][reg] + bb) * sc);
            }
        }
      } else {
        // transposed [col][72] with packed b64 writes (reg = consecutive rowL)
#pragma unroll
        for (int j = 0; j < 4; ++j) {
          const int col = wn + j * 16 + mb;
          const float bb = bias[obase + col];
#pragma unroll
          for (int i = 0; i < 4; ++i) {
            uint2 wv;
            wv.x = pack2(acc[i][j][0] + bb, acc[i][j][1] + bb);
            wv.y = pack2(acc[i][j][2] + bb, acc[i][j][3] + bb);
            *(uint2*)(Cs + col * 72 + i * 16 + 4 * g4) = wv;
          }
        }
      }
    }
    __syncthreads();
    const int rbase = row0 + h2 * 64;
    const int bb_ = rbase >> 11;
    const int nbase = rbase & (N_ - 1);
    if (z < 2) {
#pragma unroll
      for (int t = 0; t < 4; ++t) {
        const int w = t * 256 + tid;                 // 0..1023 chunks
        const int m5w = w & 31, obw = (w >> 5) & 15, kgL = w >> 9;
        const int m = (obase >> 3) + obw;            // global d-octet index
        const int hh = m / 6, dd8 = m % 6;           // kc=dd8>>1, g2=dd8&1
        const int n = nbase + kgL * 32 + m5w;
        const size_t slab = (size_t)(bb_ * H_ + hh) * (N_ * D_);
        const size_t chunk = (size_t)(((n >> 5) * 3 + (dd8 >> 1)) * 64
                                      + (dd8 & 1) * 32 + m5w);
        *(bf16x8*)(dst + slab + chunk * 8) =
            *(const bf16x8*)(Cs + (kgL * 32 + m5w) * 136 + obw * 8);
      }
    } else {
#pragma unroll
      for (int t = 0; t < 4; ++t) {
        const int w = t * 256 + tid;
        const int cw = w & 15, cb = (w >> 4) & 7, g4w = (w >> 7) & 3, hfw = w >> 9;
        const int o = obase + cb * 16 + cw;
        const int hh = o / 48, df = (o % 48) >> 4;
        const int kt = nbase >> 6;
        const size_t slab = (size_t)(bb_ * H_ + hh) * (N_ * D_);
        const size_t chunk = (size_t)(((kt * 3 + df) * 2 + hfw) * 64
                                      + g4w * 16 + cw);
        *(bf16x8*)(dst + slab + chunk * 8) =
            *(const bf16x8*)(Cs + (cb * 16 + cw) * 72 + hfw * 32 + g4w * 8);
      }
    }
  }
}

// ---- Kernel 2: barrier-free register flash attention, software-pipelined.
// P double-buffered in per-wave LDS; PV(t-1) interleaves with exp(t).
__global__ __launch_bounds__(256) void attn_mfma(
    const bf16* __restrict__ Qf, const bf16* __restrict__ Kf,
    const bf16* __restrict__ Vf, const float* __restrict__ x,
    bf16* __restrict__ Yb)
{
  __shared__ __align__(16) bf16 Ps[4 * 2 * 32 * 72];

  const int tid  = threadIdx.x;
  const int lane = tid & 63, wid = tid >> 6;
  const int m5 = lane & 31, g2h = lane >> 5;
  const int g4 = lane >> 4, c = lane & 15;
  const int bh = blockIdx.x;
  const int b_ = bh >> 4, h = bh & 15;
  const int q0 = blockIdx.y * 128 + wid * 32;
  const size_t slab = (size_t)bh * (N_ * D_);
  bf16* Pw0 = Ps + wid * 2 * (32 * 72);
  bf16* Pw1 = Pw0 + 32 * 72;

  bf16x8 qf[3];
  const int kgq = q0 >> 5;
#pragma unroll
  for (int kc = 0; kc < 3; ++kc)
    qf[kc] = *(const bf16x8*)(Qf + slab + (size_t)((kgq * 3 + kc) * 64 + lane) * 8);

  const short one_bf = (short)0x3F80;
  const bf16x8 onesf = {one_bf, one_bf, one_bf, one_bf,
                        one_bf, one_bf, one_bf, one_bf};

  f32x4 Oacc[2][3];
  f32x4 Lacc[2];
#pragma unroll
  for (int s = 0; s < 2; ++s) {
    Lacc[s] = (f32x4){0.f, 0.f, 0.f, 0.f};
#pragma unroll
    for (int df = 0; df < 3; ++df) Oacc[s][df] = (f32x4){0.f, 0.f, 0.f, 0.f};
  }

  bf16x8 kf[2][2][3];   // double-buffered K fragments
  bf16x8 vf[3][2];      // V fragments of the tile awaiting PV

  auto loadK = [&](int t, int p) {
#pragma unroll
    for (int mt = 0; mt < 2; ++mt)
#pragma unroll
      for (int kc = 0; kc < 3; ++kc)
        kf[p][mt][kc] = *(const bf16x8*)(Kf + slab +
            (size_t)(((2 * t + mt) * 3 + kc) * 64 + lane) * 8);
  };
  auto loadV = [&](int t) {
#pragma unroll
    for (int df = 0; df < 3; ++df)
#pragma unroll
      for (int hf = 0; hf < 2; ++hf)
        vf[df][hf] = *(const bf16x8*)(Vf + slab +
            (size_t)(((t * 3 + df) * 2 + hf) * 64 + lane) * 8);
  };
  auto SexpPack = [&](int p, bf16* pw) {
#pragma unroll
    for (int mt = 0; mt < 2; ++mt) {
      f32x16 st;
#pragma unroll
      for (int r = 0; r < 16; ++r) st[r] = 0.f;
      st = __builtin_amdgcn_mfma_f32_32x32x16_bf16(kf[p][mt][0], qf[0], st, 0, 0, 0);
      st = __builtin_amdgcn_mfma_f32_32x32x16_bf16(kf[p][mt][1], qf[1], st, 0, 0, 0);
      st = __builtin_amdgcn_mfma_f32_32x32x16_bf16(kf[p][mt][2], qf[2], st, 0, 0, 0);
#pragma unroll
      for (int r = 0; r < 16; ++r) st[r] = __builtin_amdgcn_exp2f(st[r]);
#pragma unroll
      for (int q = 0; q < 4; ++q) {
        uint2 w;
        w.x = pack2(st[4 * q + 0], st[4 * q + 1]);
        w.y = pack2(st[4 * q + 2], st[4 * q + 3]);
        *(uint2*)(pw + m5 * 72 + mt * 32 + 8 * q + 4 * g2h) = w;
      }
    }
  };
  auto PV = [&](const bf16* pw) {
#pragma unroll
    for (int s = 0; s < 2; ++s) {
      bf16x8 pf[2];
#pragma unroll
      for (int hf = 0; hf < 2; ++hf)
        pf[hf] = *(const bf16x8*)(pw + (s * 16 + c) * 72 + hf * 32 + 8 * g4);
#pragma unroll
      for (int df = 0; df < 3; ++df) {
        Oacc[s][df] = __builtin_amdgcn_mfma_f32_16x16x32_bf16(pf[0], vf[df][0], Oacc[s][df], 0, 0, 0);
        Oacc[s][df] = __builtin_amdgcn_mfma_f32_16x16x32_bf16(pf[1], vf[df][1], Oacc[s][df], 0, 0, 0);
      }
      Lacc[s] = __builtin_amdgcn_mfma_f32_16x16x32_bf16(pf[0], onesf, Lacc[s], 0, 0, 0);
      Lacc[s] = __builtin_amdgcn_mfma_f32_16x16x32_bf16(pf[1], onesf, Lacc[s], 0, 0, 0);
    }
  };

  // prologue: tile 0
  loadK(0, 0);
  loadK(1, 1);
  loadV(0);
  SexpPack(0, Pw0);

  // pipeline: S/exp/pack(t) overlaps PV(t-1)
#pragma unroll 2
  for (int t = 1; t < 32; ++t) {
    const int p = t & 1;
    if (t + 1 < 32) loadK(t + 1, (t + 1) & 1);
    bf16* pwCur  = p ? Pw1 : Pw0;
    bf16* pwPrev = p ? Pw0 : Pw1;
    SexpPack(p, pwCur);
    PV(pwPrev);          // consumes vf = V(t-1), P(t-1)
    loadV(t);            // refill vf for next PV (WAR-safe after PV issues)
  }
  PV(Pw1);               // tile 31 (odd)

#pragma unroll
  for (int s = 0; s < 2; ++s) {
#pragma unroll
    for (int r = 0; r < 4; ++r) {
      const float inv = 1.f / Lacc[s][r];
      const int n = q0 + s * 16 + 4 * g4 + r;
      const size_t off = ((size_t)(b_ * N_ + n)) * C_ + h * D_ + c;
#pragma unroll
      for (int df = 0; df < 3; ++df)
        Yb[off + df * 16] =
            __float2bfloat16(Oacc[s][df][r] * inv + x[off + df * 16]);
    }
  }
}

// ---- Kernel 3: O projection + residuals, m97-style staging.
__global__ __launch_bounds__(256) void gemm_out(
    const bf16* __restrict__ Yb, const bf16* __restrict__ Bw,
    const float* __restrict__ bo, const float* __restrict__ x,
    float* __restrict__ out)
{
  __shared__ __align__(16) bf16 As[128 * 64];
  __shared__ __align__(16) bf16 Bs[128 * 64];

  const int tid  = threadIdx.x;
  const int lane = tid & 63, wid = tid >> 6;
  const int wm = (wid >> 1) * 64, wn = (wid & 1) * 64;
  const int row0 = blockIdx.y * 128, col0 = blockIdx.x * 128;
  const int mb = lane & 15, g4 = lane >> 4;
  const int srow = lane >> 3;
  const int schunk = (lane & 7) ^ (srow & 7);

  f32x4 acc[4][4];
#pragma unroll
  for (int i = 0; i < 4; ++i)
#pragma unroll
    for (int j = 0; j < 4; ++j) acc[i][j] = (f32x4){0.f, 0.f, 0.f, 0.f};

  for (int k0 = 0; k0 < C_; k0 += 64) {
#pragma unroll
    for (int t = 0; t < 4; ++t) {
      const int rt = wid * 32 + t * 8;
      gload_lds16(Yb + (size_t)(row0 + rt + srow) * C_ + k0 + schunk * 8,
                  As + rt * 64);
      gload_lds16(Bw + (size_t)(col0 + rt + srow) * C_ + k0 + schunk * 8,
                  Bs + rt * 64);
    }
    __syncthreads();
#pragma unroll
    for (int ks = 0; ks < 2; ++ks) {
      const int kchunk = ks * 4 + g4;
      bf16x8 af[4], bfr[4];
#pragma unroll
      for (int i = 0; i < 4; ++i) {
        const int row = wm + i * 16 + mb;
        af[i] = *(const bf16x8*)(As + row * 64 + (kchunk ^ (row & 7)) * 8);
      }
#pragma unroll
      for (int j = 0; j < 4; ++j) {
        const int col = wn + j * 16 + mb;
        bfr[j] = *(const bf16x8*)(Bs + col * 64 + (kchunk ^ (col & 7)) * 8);
      }
#pragma unroll
      for (int i = 0; i < 4; ++i)
#pragma unroll
        for (int j = 0; j < 4; ++j)
          acc[i][j] = __builtin_amdgcn_mfma_f32_16x16x32_bf16(af[i], bfr[j], acc[i][j], 0, 0, 0);
    }
    __syncthreads();
  }

  const int crow = g4 * 4;
#pragma unroll
  for (int j = 0; j < 4; ++j) {
    const int o = col0 + wn + j * 16 + mb;
    const float bb = bo[o];
#pragma unroll
    for (int i = 0; i < 4; ++i) {
#pragma unroll
      for (int reg = 0; reg < 4; ++reg) {
        const int r = row0 + wm + i * 16 + crow + reg;
        const size_t off = (size_t)r * C_ + o;
        out[off] = acc[i][j][reg] + bb + __bfloat162float(Yb[off]) + x[off];
      }
    }
  }
}

extern "C" void kernel_launch(void* const* d_in, const int* in_sizes, int n_in,
                              void* d_out, int out_size, void* d_ws, size_t ws_size,
                              hipStream_t stream)
{
  const float* x  = (const float*)d_in[0];
  const float* wq = (const float*)d_in[1];
  const float* bq = (const float*)d_in[2];
  const float* wk = (const float*)d_in[3];
  const float* bk = (const float*)d_in[4];
  const float* wv = (const float*)d_in[5];
  const float* bv = (const float*)d_in[6];
  const float* wo = (const float*)d_in[7];
  const float* bo = (const float*)d_in[8];
  float* out = (float*)d_out;

  const size_t nEl = (size_t)B_ * N_ * C_;      // 6,291,456
  const size_t wEl = (size_t)C_ * C_;           // 589,824
  bf16* Q     = (bf16*)d_ws;                    // MFMA-fragment layout
  bf16* K     = Q + nEl;
  bf16* V     = K + nEl;
  bf16* Yb    = V + nEl;                        // [b][n][c] bf16 (y = attn+x)
  bf16* xb    = Yb + nEl;                       // [8192][768] bf16
  bf16* wqkvb = xb + nEl;                       // [2304][768] bf16 stacked
  bf16* wob   = wqkvb + 3 * wEl;                // [768][768] bf16

  dim3 gcvt(768, 5);
  cvt_bf16<<<gcvt, dim3(256), 0, stream>>>(x, wq, wk, wv, wo, xb, wqkvb, wob);

  dim3 gqkv(18, 64);
  gemm_qkv<<<gqkv, dim3(256), 0, stream>>>(xb, wqkvb, bq, bk, bv, Q, K, V);

  dim3 gattn(B_ * H_, N_ / 128);                // (64, 16)
  attn_mfma<<<gattn, dim3(256), 0, stream>>>(Q, K, V, x, Yb);

  dim3 gout(6, 64);
  gemm_out<<<gout, dim3(256), 0, stream>>>(Yb, wob, bo, x, out);
}